// Round 1
// baseline (113.913 us; speedup 1.0000x reference)
//
#include <hip/hip_runtime.h>

#define DEG 16
#define ATOMS_PER_BLOCK 16
#define EPS_F 1e-12f

__global__ void mbp_zero_kernel(float* out) {
    if (threadIdx.x == 0) out[0] = 0.0f;
}

__global__ __launch_bounds__(256) void ManyBodyPotential_85143431675992_kernel(
    const float* __restrict__ pos,      // (n_atoms, 3)
    const int*   __restrict__ target,   // (n_atoms*DEG,)  = edge_index[1]
    const int*   __restrict__ elem,     // (n_atoms,)
    const int*   __restrict__ plt,      // (3,3) row-major
    const float* __restrict__ k_angle,  // (6,)
    const float* __restrict__ cos0,     // (6,)
    float*       __restrict__ out,
    int n_atoms)
{
    // Pre-folded per-(ej,ek) tables: 9 entries each.
    __shared__ float ka_tab[9];
    __shared__ float c0_tab[9];
    // Per-atom neighbor staging (16 atoms/block, +1 pad for bank spread).
    __shared__ float sx[ATOMS_PER_BLOCK][DEG + 1];
    __shared__ float sy[ATOMS_PER_BLOCK][DEG + 1];
    __shared__ float sz[ATOMS_PER_BLOCK][DEG + 1];
    __shared__ float sn[ATOMS_PER_BLOCK][DEG + 1];
    __shared__ int   se[ATOMS_PER_BLOCK][DEG + 1];
    __shared__ float wsum[4];

    const int t = threadIdx.x;
    if (t < 9) {
        const int p = plt[t];          // plt[ej][ek], row-major, symmetric
        ka_tab[t] = k_angle[p];
        c0_tab[t] = cos0[p];
    }

    const int a    = t >> 4;           // local atom 0..15
    const int j    = t & 15;           // neighbor slot 0..15
    const int atom = blockIdx.x * ATOMS_PER_BLOCK + a;
    const bool active = (atom < n_atoms);

    float rx = 0.f, ry = 0.f, rz = 0.f, rn = 0.f;
    int   ej = 0;
    if (active) {
        const float pix = pos[atom * 3 + 0];
        const float piy = pos[atom * 3 + 1];
        const float piz = pos[atom * 3 + 2];
        const int   tj  = target[atom * DEG + j];
        rx = pos[tj * 3 + 0] - pix;
        ry = pos[tj * 3 + 1] - piy;
        rz = pos[tj * 3 + 2] - piz;
        rn = sqrtf(rx * rx + ry * ry + rz * rz);
        ej = elem[tj];
        sx[a][j] = rx; sy[a][j] = ry; sz[a][j] = rz;
        sn[a][j] = rn; se[a][j] = ej;
    }
    __syncthreads();

    float acc = 0.0f;
    if (active) {
        const int ej3 = ej * 3;
        #pragma unroll
        for (int k = 0; k < DEG; ++k) {
            const float ox = sx[a][k];
            const float oy = sy[a][k];
            const float oz = sz[a][k];
            const float on = sn[a][k];
            const int   ek = se[a][k];
            const float dt = rx * ox + ry * oy + rz * oz;
            const float ct = dt / (rn * on + EPS_F);   // exact reference math
            const int   idx = ej3 + ek;
            const float d  = ct - c0_tab[idx];
            const float e  = ka_tab[idx] * d * d;
            if (k != j) acc += e;                      // mask self-pair
        }
    }

    // Wave(64)-level shuffle reduction, then block reduction, one atomic/block.
    #pragma unroll
    for (int off = 32; off > 0; off >>= 1)
        acc += __shfl_down(acc, off, 64);
    const int wave = t >> 6;
    if ((t & 63) == 0) wsum[wave] = acc;
    __syncthreads();
    if (t == 0) {
        const float s = wsum[0] + wsum[1] + wsum[2] + wsum[3];
        atomicAdd(out, s);
    }
}

extern "C" void kernel_launch(void* const* d_in, const int* in_sizes, int n_in,
                              void* d_out, int out_size, void* d_ws, size_t ws_size,
                              hipStream_t stream) {
    const float* pos     = (const float*)d_in[0];
    const int*   edge    = (const int*)d_in[1];   // (2, n_edges) flat
    const int*   elem    = (const int*)d_in[2];
    const int*   plt     = (const int*)d_in[3];
    const float* k_angle = (const float*)d_in[4];
    const float* cos0    = (const float*)d_in[5];
    float*       out     = (float*)d_out;

    const int n_atoms = in_sizes[0] / 3;
    const int n_edges = in_sizes[1] / 2;
    const int* target = edge + n_edges;           // edge_index[1]

    mbp_zero_kernel<<<1, 64, 0, stream>>>(out);

    const int blocks = (n_atoms + ATOMS_PER_BLOCK - 1) / ATOMS_PER_BLOCK;
    ManyBodyPotential_85143431675992_kernel<<<blocks, 256, 0, stream>>>(
        pos, target, elem, plt, k_angle, cos0, out, n_atoms);
}

// Round 2
// 81.159 us; speedup vs baseline: 1.4036x; 1.4036x over previous
//
#include <hip/hip_runtime.h>

#define DEG 16
#define ATOMS_PER_BLOCK 16
#define NBLOCKS 2048
#define EPS_F 1e-12f

__global__ __launch_bounds__(256) void ManyBodyPotential_85143431675992_kernel(
    const float* __restrict__ pos,      // (n_atoms, 3)
    const int*   __restrict__ target,   // (n_atoms*DEG,)  = edge_index[1]
    const int*   __restrict__ elem,     // (n_atoms,)
    const int*   __restrict__ plt,      // (3,3) row-major
    const float* __restrict__ k_angle,  // (6,)
    const float* __restrict__ cos0,     // (6,)
    float*       __restrict__ partials, // (gridDim.x,) distinct slots, no contention
    float*       __restrict__ out,      // fallback atomic target (ws too small)
    int n_atoms)
{
    __shared__ float  ka_tab[9];
    __shared__ float  c0_tab[9];
    // xyz + norm packed for ds_read_b128; +1 float4 pad per row.
    __shared__ float4 s4[ATOMS_PER_BLOCK][DEG + 1];
    __shared__ int    se[ATOMS_PER_BLOCK][DEG + 1];
    __shared__ float  wsum[4];

    const int t = threadIdx.x;
    if (t < 9) {
        const int p = plt[t];          // plt[ej][ek], symmetric
        ka_tab[t] = k_angle[p];
        c0_tab[t] = cos0[p];
    }

    const int a = t >> 4;              // local atom 0..15
    const int j = t & 15;              // neighbor slot 0..15
    const int n_groups = (n_atoms + ATOMS_PER_BLOCK - 1) / ATOMS_PER_BLOCK;

    float acc = 0.0f;

    for (int g = blockIdx.x; g < n_groups; g += gridDim.x) {
        const int atom = g * ATOMS_PER_BLOCK + a;
        const bool active = (atom < n_atoms);

        float rx = 0.f, ry = 0.f, rz = 0.f, rn = 0.f;
        int   ej = 0;
        if (active) {
            const float pix = pos[atom * 3 + 0];
            const float piy = pos[atom * 3 + 1];
            const float piz = pos[atom * 3 + 2];
            const int   tj  = target[atom * DEG + j];  // coalesced
            rx = pos[tj * 3 + 0] - pix;
            ry = pos[tj * 3 + 1] - piy;
            rz = pos[tj * 3 + 2] - piz;
            rn = sqrtf(rx * rx + ry * ry + rz * rz);
            ej = elem[tj];
            s4[a][j] = make_float4(rx, ry, rz, rn);
            se[a][j] = ej;
        }
        __syncthreads();

        if (active) {
            const int ej3 = ej * 3;
            #pragma unroll
            for (int k = 0; k < DEG; ++k) {
                const float4 o  = s4[a][k];            // ds_read_b128, broadcast
                const int    ek = se[a][k];
                const float  dt = rx * o.x + ry * o.y + rz * o.z;
                const float  ct = dt / (rn * o.w + EPS_F);  // exact reference math
                const int    idx = ej3 + ek;
                const float  d  = ct - c0_tab[idx];
                const float  e  = ka_tab[idx] * d * d;
                if (k != j) acc += e;                  // mask self-pair
            }
        }
        __syncthreads();                               // before LDS overwrite next iter
    }

    // Wave(64) shuffle reduction -> block reduction -> one partial per block.
    #pragma unroll
    for (int off = 32; off > 0; off >>= 1)
        acc += __shfl_down(acc, off, 64);
    const int wave = t >> 6;
    if ((t & 63) == 0) wsum[wave] = acc;
    __syncthreads();
    if (t == 0) {
        const float s = wsum[0] + wsum[1] + wsum[2] + wsum[3];
        if (partials) partials[blockIdx.x] = s;        // distinct address per block
        else          atomicAdd(out, s);               // fallback only
    }
}

__global__ __launch_bounds__(512) void mbp_reduce_kernel(
    const float* __restrict__ partials, float* __restrict__ out, int n)
{
    __shared__ float wsum[8];
    const int t = threadIdx.x;
    float acc = 0.0f;
    for (int i = t; i < n; i += 512) acc += partials[i];
    #pragma unroll
    for (int off = 32; off > 0; off >>= 1)
        acc += __shfl_down(acc, off, 64);
    if ((t & 63) == 0) wsum[t >> 6] = acc;
    __syncthreads();
    if (t == 0) {
        float s = 0.0f;
        #pragma unroll
        for (int i = 0; i < 8; ++i) s += wsum[i];
        out[0] = s;
    }
}

__global__ void mbp_zero_kernel(float* out) {
    if (threadIdx.x == 0) out[0] = 0.0f;
}

extern "C" void kernel_launch(void* const* d_in, const int* in_sizes, int n_in,
                              void* d_out, int out_size, void* d_ws, size_t ws_size,
                              hipStream_t stream) {
    const float* pos     = (const float*)d_in[0];
    const int*   edge    = (const int*)d_in[1];   // (2, n_edges) flat
    const int*   elem    = (const int*)d_in[2];
    const int*   plt     = (const int*)d_in[3];
    const float* k_angle = (const float*)d_in[4];
    const float* cos0    = (const float*)d_in[5];
    float*       out     = (float*)d_out;

    const int n_atoms = in_sizes[0] / 3;
    const int n_edges = in_sizes[1] / 2;
    const int* target = edge + n_edges;           // edge_index[1]

    const bool ws_ok = (d_ws != nullptr) && (ws_size >= NBLOCKS * sizeof(float));
    float* partials = ws_ok ? (float*)d_ws : nullptr;

    if (!ws_ok) mbp_zero_kernel<<<1, 64, 0, stream>>>(out);

    ManyBodyPotential_85143431675992_kernel<<<NBLOCKS, 256, 0, stream>>>(
        pos, target, elem, plt, k_angle, cos0, partials, out, n_atoms);

    if (ws_ok)
        mbp_reduce_kernel<<<1, 512, 0, stream>>>(partials, out, NBLOCKS);
}

// Round 3
// 79.637 us; speedup vs baseline: 1.4304x; 1.0191x over previous
//
#include <hip/hip_runtime.h>

#define DEG 16
#define ATOMS_PER_BLOCK 16

__global__ __launch_bounds__(256) void ManyBodyPotential_85143431675992_kernel(
    const float* __restrict__ pos,      // (n_atoms, 3)
    const int*   __restrict__ target,   // (n_atoms*DEG,)  = edge_index[1]
    const int*   __restrict__ elem,     // (n_atoms,)
    const int*   __restrict__ plt,      // (3,3) row-major, symmetric
    const float* __restrict__ k_angle,  // (6,)
    const float* __restrict__ cos0,     // (6,)
    float*       __restrict__ partials, // (gridDim.x,) distinct slots
    float*       __restrict__ out,      // fallback atomic target
    int n_atoms)
{
    __shared__ float  ka_tab[9];
    __shared__ float  c0_tab[9];
    // Per neighbor: unit vector + element-as-float in .w  (ds_read_b128)
    __shared__ float4 s4[ATOMS_PER_BLOCK][DEG + 1];   // +1 float4 row pad
    __shared__ float  wsum[4];

    const int t = threadIdx.x;
    if (t < 9) {
        const int p = plt[t];
        ka_tab[t] = k_angle[p];
        c0_tab[t] = cos0[p];
    }

    const int a    = t >> 4;             // local atom 0..15
    const int j    = t & 15;             // neighbor slot 0..15
    const int atom = blockIdx.x * ATOMS_PER_BLOCK + a;
    const bool active = (atom < n_atoms);

    float ux = 0.f, uy = 0.f, uz = 0.f;
    int   ej = 0;
    if (active) {
        const float pix = pos[atom * 3 + 0];
        const float piy = pos[atom * 3 + 1];
        const float piz = pos[atom * 3 + 2];
        const int   tj  = target[atom * DEG + j];      // coalesced
        const float dx  = pos[tj * 3 + 0] - pix;
        const float dy  = pos[tj * 3 + 1] - piy;
        const float dz  = pos[tj * 3 + 2] - piz;
        const float r2  = dx * dx + dy * dy + dz * dz;
        // r2==0 (self-edge / coincident atoms): reference gives cos=0 for any
        // pair involving this edge; zero unit vector reproduces that exactly.
        const float rinv = (r2 > 0.f) ? rsqrtf(r2) : 0.f;
        ux = dx * rinv; uy = dy * rinv; uz = dz * rinv;
        ej = elem[tj];
        s4[a][j] = make_float4(ux, uy, uz, (float)ej);
    }
    __syncthreads();

    float acc = 0.0f;
    if (active) {
        // Hoist this thread's (ej, *) coefficient row into registers.
        const int   r   = ej * 3;
        const float ka0 = ka_tab[r + 0], ka1 = ka_tab[r + 1], ka2 = ka_tab[r + 2];
        const float c00 = c0_tab[r + 0], c01 = c0_tab[r + 1], c02 = c0_tab[r + 2];

        // Symmetry: e(j,k)==e(k,j).  Offsets d=1..7 cover each unordered
        // pair once (weight 2); d=8 pairs appear twice across j (weight 1).
        float acc2 = 0.0f, acc8 = 0.0f;
        #pragma unroll
        for (int d = 1; d <= 8; ++d) {
            const int    k  = (j + d) & 15;
            const float4 o  = s4[a][k];
            const float  ka = (o.w == 1.0f) ? ka1 : ((o.w == 2.0f) ? ka2 : ka0);
            const float  c0 = (o.w == 1.0f) ? c01 : ((o.w == 2.0f) ? c02 : c00);
            const float  ct = ux * o.x + uy * o.y + uz * o.z;   // cos(theta)
            const float  dd = ct - c0;
            const float  e  = ka * dd * dd;
            if (d < 8) acc2 += e; else acc8 = e;
        }
        acc = 2.0f * acc2 + acc8;
    }

    // Wave(64) shuffle reduction -> block reduction -> one partial per block.
    #pragma unroll
    for (int off = 32; off > 0; off >>= 1)
        acc += __shfl_down(acc, off, 64);
    if ((t & 63) == 0) wsum[t >> 6] = acc;
    __syncthreads();
    if (t == 0) {
        const float s = wsum[0] + wsum[1] + wsum[2] + wsum[3];
        if (partials) partials[blockIdx.x] = s;
        else          atomicAdd(out, s);
    }
}

__global__ __launch_bounds__(1024) void mbp_reduce_kernel(
    const float* __restrict__ partials, float* __restrict__ out, int n)
{
    __shared__ float wsum[16];
    const int t = threadIdx.x;
    float acc = 0.0f;
    for (int i = t; i < n; i += 1024) acc += partials[i];
    #pragma unroll
    for (int off = 32; off > 0; off >>= 1)
        acc += __shfl_down(acc, off, 64);
    if ((t & 63) == 0) wsum[t >> 6] = acc;
    __syncthreads();
    if (t == 0) {
        float s = 0.0f;
        #pragma unroll
        for (int i = 0; i < 16; ++i) s += wsum[i];
        out[0] = s;
    }
}

__global__ void mbp_zero_kernel(float* out) {
    if (threadIdx.x == 0) out[0] = 0.0f;
}

extern "C" void kernel_launch(void* const* d_in, const int* in_sizes, int n_in,
                              void* d_out, int out_size, void* d_ws, size_t ws_size,
                              hipStream_t stream) {
    const float* pos     = (const float*)d_in[0];
    const int*   edge    = (const int*)d_in[1];   // (2, n_edges) flat
    const int*   elem    = (const int*)d_in[2];
    const int*   plt     = (const int*)d_in[3];
    const float* k_angle = (const float*)d_in[4];
    const float* cos0    = (const float*)d_in[5];
    float*       out     = (float*)d_out;

    const int n_atoms = in_sizes[0] / 3;
    const int n_edges = in_sizes[1] / 2;
    const int* target = edge + n_edges;           // edge_index[1]

    const int n_blocks = (n_atoms + ATOMS_PER_BLOCK - 1) / ATOMS_PER_BLOCK;  // 3125

    const bool ws_ok = (d_ws != nullptr) && (ws_size >= (size_t)n_blocks * sizeof(float));
    float* partials = ws_ok ? (float*)d_ws : nullptr;

    if (!ws_ok) mbp_zero_kernel<<<1, 64, 0, stream>>>(out);

    ManyBodyPotential_85143431675992_kernel<<<n_blocks, 256, 0, stream>>>(
        pos, target, elem, plt, k_angle, cos0, partials, out, n_atoms);

    if (ws_ok)
        mbp_reduce_kernel<<<1, 1024, 0, stream>>>(partials, out, n_blocks);
}